// Round 2
// baseline (1200.557 us; speedup 1.0000x reference)
//
#include <hip/hip_runtime.h>

// Top2Gating: B=4, N=4096, D=1024, E=64, capacity=128
// Outputs (flat in d_out): dispatch [B,N,E,C], combine [B,N,E,C], loss, z_loss

#define B_DIM 4
#define N_DIM 4096
#define D_DIM 1024
#define E_DIM 64
#define CAP   128
#define NTOK  (B_DIM * N_DIM)   // 16384
#define TM    32                 // tokens per gating block
#define TK    64                 // k-chunk

// ---------------- ws layout (bytes) ----------------
#define WS_IDX1  0
#define WS_IDX2  65536
#define WS_G1    131072
#define WS_G2    196608
#define WS_POS1  262144
#define WS_POS2  327680
#define WS_CNT1  393216   // 256 ints
#define WS_DENS  394240   // 256 floats (atomic, zeroed by zero_kernel)
#define WS_ZSUM  395264   // 1 float   (atomic, zeroed by zero_kernel)

// Kernel A: vectorized zero of the dense output (the mandatory 1.07 GB write).
// hipMemsetAsync's fillBufferAligned showed 4x write amplification (4.295 GB
// for a 1.074 GB buffer, 690 us); this float4 fill writes exactly 1.074 GB.
// Also zeroes the small atomic accumulators (block 0).
__global__ __launch_bounds__(256) void zero_kernel(float4* __restrict__ out,
                                                   float* __restrict__ accum) {
  const size_t base = (size_t)blockIdx.x * (256 * 32) + threadIdx.x;
  const float4 z = make_float4(0.f, 0.f, 0.f, 0.f);
#pragma unroll
  for (int i = 0; i < 32; ++i) out[base + (size_t)i * 256] = z;
  if (blockIdx.x == 0 && threadIdx.x < 257) accum[threadIdx.x] = 0.f;  // dens[256]+zsum
}

// Kernel B: router GEMM (fp64 accumulate) + softmax/top2 per token.
// grid 512 blocks x 256 threads; each block handles 32 tokens x all 64 experts.
__global__ __launch_bounds__(256) void gating_kernel(
    const float* __restrict__ x, const float* __restrict__ w,
    int* __restrict__ idx1, int* __restrict__ idx2,
    float* __restrict__ g1o, float* __restrict__ g2o,
    int* __restrict__ pos2, float* __restrict__ dens, float* __restrict__ zsum) {
  __shared__ float  As[TM][68];        // x chunk [tok][k], pad 68 (16B-aligned rows)
  __shared__ float  Bs[TK][E_DIM];     // w chunk [k][e]
  __shared__ double Ld[TM][65];        // fp64 logits [tok][e]

  const int t = threadIdx.x;
  const int tokBase = blockIdx.x * TM;
  const int e4 = t & 15;               // expert-quad id   -> e0 = 4*e4
  const int tokg = t >> 4;             // token-pair id    -> tok0 = 2*tokg
  const int tok0 = 2 * tokg, e0 = 4 * e4;

  double acc[2][4] = {};

  for (int k0 = 0; k0 < D_DIM; k0 += TK) {
    // stage A: 32 rows x 64 cols, 2 float4 per thread
    {
      const int d4 = t & 15, row = t >> 4;  // row 0..15 (+16)
      float4 va = *(const float4*)(x + (size_t)(tokBase + row) * D_DIM + k0 + 4 * d4);
      float4 vb = *(const float4*)(x + (size_t)(tokBase + row + 16) * D_DIM + k0 + 4 * d4);
      *(float4*)&As[row][4 * d4] = va;
      *(float4*)&As[row + 16][4 * d4] = vb;
    }
    // stage B: 64 rows x 64 experts = 1024 float4, contiguous in w
    {
      const float4* wsrc = (const float4*)(w + (size_t)k0 * E_DIM);
      float4* bdst = (float4*)&Bs[0][0];
      bdst[t]       = wsrc[t];
      bdst[t + 256] = wsrc[t + 256];
      bdst[t + 512] = wsrc[t + 512];
      bdst[t + 768] = wsrc[t + 768];
    }
    __syncthreads();
#pragma unroll 8
    for (int kk = 0; kk < TK; ++kk) {
      float a0 = As[tok0][kk], a1 = As[tok0 + 1][kk];
      float4 bv = *(float4*)&Bs[kk][e0];
      double da0 = (double)a0, da1 = (double)a1;
      double b0 = (double)bv.x, b1 = (double)bv.y, b2 = (double)bv.z, b3 = (double)bv.w;
      acc[0][0] += da0 * b0; acc[0][1] += da0 * b1; acc[0][2] += da0 * b2; acc[0][3] += da0 * b3;
      acc[1][0] += da1 * b0; acc[1][1] += da1 * b1; acc[1][2] += da1 * b2; acc[1][3] += da1 * b3;
    }
    __syncthreads();
  }

  // dump fp64 logits to LDS
#pragma unroll
  for (int i = 0; i < 2; ++i)
#pragma unroll
    for (int j = 0; j < 4; ++j) Ld[tok0 + i][e0 + j] = acc[i][j];
  __syncthreads();

  // softmax/top2: 4 waves, 8 tokens each; lane = expert
  const int wave = t >> 6;
  const int lane = t & 63;
  const int b = tokBase >> 12;  // /4096 (blocks never span batches)
  float densacc = 0.f, zacc = 0.f;

  for (int s = 0; s < 8; ++s) {
    const int tok = wave * 8 + s;
    const double l = Ld[tok][lane];

    // argmax (first-index tie-break) in fp64
    double mv = l; int mi = lane;
#pragma unroll
    for (int off = 32; off; off >>= 1) {
      double ov = __shfl_xor(mv, off);
      int oi = __shfl_xor(mi, off);
      if (ov > mv || (ov == mv && oi < mi)) { mv = ov; mi = oi; }
    }
    float p = expf((float)(l - mv));
    float sum = p;
#pragma unroll
    for (int off = 32; off; off >>= 1) sum += __shfl_xor(sum, off);

    // second argmax excluding mi
    double l2 = (lane == mi) ? -1.0e300 : l;
    double mv2 = l2; int mi2 = lane;
#pragma unroll
    for (int off = 32; off; off >>= 1) {
      double ov = __shfl_xor(mv2, off);
      int oi = __shfl_xor(mi2, off);
      if (ov > mv2 || (ov == mv2 && oi < mi2)) { mv2 = ov; mi2 = oi; }
    }

    float gate1 = 1.0f / sum;                        // exp(0)/sum
    float gate2 = expf((float)(mv2 - mv)) / sum;
    float denom = gate1 + gate2 + 1e-9f;
    float g1n = gate1 / denom, g2n = gate2 / denom;
    int i2eff = (g2n > 0.2f) ? mi2 : -1;             // second-expert threshold policy
    float lse = (float)mv + logf(sum);

    densacc += p;                                    // density_proxy sum (per expert=lane)
    if (lane == 0) {
      const int gt = tokBase + tok;
      idx1[gt] = mi; idx2[gt] = i2eff;
      g1o[gt] = g1n; g2o[gt] = g2n;
      pos2[gt] = (1 << 20);                          // default: dropped
      zacc += lse;
    }
  }
  atomicAdd(&dens[(b << 6) + lane], densacc);
  if (lane == 0) atomicAdd(zsum, zacc);
}

// Kernel C: capacity scan. One wave per (b,e); sequential over token order with
// ballot-based prefix counts. Phase 2 (top-2) offset by min(count1, CAP).
__global__ __launch_bounds__(64) void scan_kernel(
    const int* __restrict__ idx1, const int* __restrict__ idx2,
    int* __restrict__ pos1, int* __restrict__ pos2, int* __restrict__ cnt1) {
  const int bid = blockIdx.x;      // 0..255
  const int b = bid >> 6, e = bid & 63;
  const int lane = threadIdx.x;
  const int base = b * N_DIM;
  const unsigned long long lmask = (1ull << lane) - 1ull;

  int run = 0;
#pragma unroll 4
  for (int ch = 0; ch < N_DIM / 64; ++ch) {
    const int tok = base + ch * 64 + lane;
    const bool m = (idx1[tok] == e);
    unsigned long long bal = __ballot(m);
    if (m) pos1[tok] = run + __popcll(bal & lmask);
    run += __popcll(bal);
  }
  if (lane == 0) cnt1[bid] = run;        // pre-truncation count (for aux loss)

  const int off = run < CAP ? run : CAP; // mask_1_count = min(count, capacity)
  int run2 = 0;
#pragma unroll 4
  for (int ch = 0; ch < N_DIM / 64; ++ch) {
    const int tok = base + ch * 64 + lane;
    const bool m = (idx2[tok] == e);
    unsigned long long bal = __ballot(m);
    if (m) pos2[tok] = off + run2 + __popcll(bal & lmask);
    run2 += __popcll(bal);
  }
}

// Kernel D: scatter nonzeros into the (pre-zeroed) dense output + scalar losses.
__global__ __launch_bounds__(256) void scatter_kernel(
    const int* __restrict__ idx1, const int* __restrict__ idx2,
    const float* __restrict__ g1, const float* __restrict__ g2,
    const int* __restrict__ pos1, const int* __restrict__ pos2,
    const int* __restrict__ cnt1, const float* __restrict__ dens,
    const float* __restrict__ zsum, float* __restrict__ out, size_t half) {
  const int t = blockIdx.x * 256 + threadIdx.x;  // token 0..16383
  float* dispatch = out;
  float* combine = out + half;

  const int i1 = idx1[t], p1 = pos1[t];
  if (p1 < CAP) {
    const size_t off = ((size_t)t * E_DIM + i1) * CAP + p1;
    combine[off] = g1[t];
    dispatch[off] = 1.0f;
  }
  const int i2 = idx2[t];
  if (i2 >= 0) {
    const int p2 = pos2[t];
    if (p2 < CAP) {
      const size_t off = ((size_t)t * E_DIM + i2) * CAP + p2;
      combine[off] = g2[t];
      dispatch[off] = 1.0f;
    }
  }

  if (blockIdx.x == 0 && threadIdx.x < 64) {
    const int lane = threadIdx.x;
    float partial = 0.f;
#pragma unroll
    for (int k = 0; k < 4; ++k) {
      const int i = lane * 4 + k;
      partial += dens[i] * (float)cnt1[i];
    }
#pragma unroll
    for (int off = 32; off; off >>= 1) partial += __shfl_xor(partial, off);
    if (lane == 0) {
      // loss = sum(S*C) / (N * B*E) = sum / 1048576; z = sum(lse)/B
      out[2 * half]     = partial * (1.0f / 1048576.0f);
      out[2 * half + 1] = zsum[0] * 0.25f;
    }
  }
}

extern "C" void kernel_launch(void* const* d_in, const int* in_sizes, int n_in,
                              void* d_out, int out_size, void* d_ws, size_t ws_size,
                              hipStream_t stream) {
  const float* x = (const float*)d_in[0];
  const float* w = (const float*)d_in[1];
  float* out = (float*)d_out;
  char* ws = (char*)d_ws;

  int*   idx1 = (int*)(ws + WS_IDX1);
  int*   idx2 = (int*)(ws + WS_IDX2);
  float* g1   = (float*)(ws + WS_G1);
  float* g2   = (float*)(ws + WS_G2);
  int*   pos1 = (int*)(ws + WS_POS1);
  int*   pos2 = (int*)(ws + WS_POS2);
  int*   cnt1 = (int*)(ws + WS_CNT1);
  float* dens = (float*)(ws + WS_DENS);
  float* zsum = (float*)(ws + WS_ZSUM);

  const size_t half = ((size_t)out_size - 2) / 2;  // 134217728

  // zero the dense output: 2*half floats = 67108864 float4 / (256 thr * 32 f4)
  // = 8192 blocks. Loss scalars are overwritten unconditionally by scatter.
  zero_kernel<<<8192, 256, 0, stream>>>((float4*)out, dens);

  gating_kernel<<<NTOK / TM, 256, 0, stream>>>(x, w, idx1, idx2, g1, g2, pos2, dens, zsum);
  scan_kernel<<<B_DIM * E_DIM, 64, 0, stream>>>(idx1, idx2, pos1, pos2, cnt1);
  scatter_kernel<<<NTOK / 256, 256, 0, stream>>>(idx1, idx2, g1, g2, pos1, pos2,
                                                 cnt1, dens, zsum, out, half);
}

// Round 3
// 1111.258 us; speedup vs baseline: 1.0804x; 1.0804x over previous
//
#include <hip/hip_runtime.h>

// Top2Gating: B=4, N=4096, D=1024, E=64, capacity=128
// Outputs (flat in d_out): dispatch [B,N,E,C], combine [B,N,E,C], loss, z_loss
//
// dur_us model (R2 post-mortem): ~715 us is harness poison/restore (0xAA fill
// of d_out shows as 690 us fillBufferAligned, 4.295 GB write). Controllable
// graph time ~485 us. This round: overlap the mandatory 1.07 GB zero-write
// with the gating GEMM via block-role specialization in ONE kernel, and fold
// scatter+loss into the scan kernel.

#define B_DIM 4
#define N_DIM 4096
#define D_DIM 1024
#define E_DIM 64
#define CAP   128
#define NTOK  (B_DIM * N_DIM)   // 16384
#define TM    32                 // tokens per gating block
#define TK    64                 // k-chunk
#define GATE_BLOCKS 512          // NTOK/TM
#define ZERO_BLOCKS 8192         // 2*half floats / (256 thr * 32 float4)

// ---------------- ws layout (bytes) ----------------
#define WS_IDX1  0
#define WS_IDX2  65536
#define WS_G1    131072
#define WS_G2    196608
#define WS_DENS  262144   // 256 floats (atomic; zeroed by tiny memset)
#define WS_ZSUM  263168   // 1 float

// Kernel 1: block-role fused kernel.
//  blocks [0, 512):    router GEMM (fp64 accumulate) + softmax/top2 per token
//  blocks [512, 8704): vectorized zero of the 1.07 GB dense output
// LDS: A/B staging (25088 B) overlaid with fp64 logits (16640 B) -> 6 blk/CU.
__global__ __launch_bounds__(256) void fused_gating_zero(
    const float* __restrict__ x, const float* __restrict__ w,
    int* __restrict__ idx1, int* __restrict__ idx2,
    float* __restrict__ g1o, float* __restrict__ g2o,
    float* __restrict__ dens, float* __restrict__ zsum,
    float* __restrict__ out, size_t half) {
  __shared__ __align__(16) char smem[(TM * 68 + TK * E_DIM) * 4];  // 25088 B
  const int t = threadIdx.x;

  if (blockIdx.x >= GATE_BLOCKS) {
    // ---- zero role: write exactly 2*half zeros, float4-vectorized ----
    const int zb = blockIdx.x - GATE_BLOCKS;
    float4* o4 = (float4*)out;
    const size_t base = (size_t)zb * (256 * 32) + t;
    const float4 z = make_float4(0.f, 0.f, 0.f, 0.f);
#pragma unroll
    for (int i = 0; i < 32; ++i) o4[base + (size_t)i * 256] = z;
    if (zb == 0 && t == 0) { out[2 * half] = 0.f; out[2 * half + 1] = 0.f; }
    return;
  }

  // ---- gating role ----
  float (*As)[68]   = (float(*)[68])smem;                    // [TM][68]
  float (*Bs)[E_DIM] = (float(*)[E_DIM])(smem + TM * 68 * 4); // [TK][64]
  double (*Ld)[65]  = (double(*)[65])smem;                   // overlaid, used after k-loop

  const int tokBase = blockIdx.x * TM;
  const int e4 = t & 15;               // expert-quad id   -> e0 = 4*e4
  const int tokg = t >> 4;             // token-pair id    -> tok0 = 2*tokg
  const int tok0 = 2 * tokg, e0 = 4 * e4;

  double acc[2][4] = {};

  for (int k0 = 0; k0 < D_DIM; k0 += TK) {
    {
      const int d4 = t & 15, row = t >> 4;  // row 0..15 (+16)
      float4 va = *(const float4*)(x + (size_t)(tokBase + row) * D_DIM + k0 + 4 * d4);
      float4 vb = *(const float4*)(x + (size_t)(tokBase + row + 16) * D_DIM + k0 + 4 * d4);
      *(float4*)&As[row][4 * d4] = va;
      *(float4*)&As[row + 16][4 * d4] = vb;
    }
    {
      const float4* wsrc = (const float4*)(w + (size_t)k0 * E_DIM);
      float4* bdst = (float4*)&Bs[0][0];
      bdst[t]       = wsrc[t];
      bdst[t + 256] = wsrc[t + 256];
      bdst[t + 512] = wsrc[t + 512];
      bdst[t + 768] = wsrc[t + 768];
    }
    __syncthreads();
#pragma unroll 8
    for (int kk = 0; kk < TK; ++kk) {
      float a0 = As[tok0][kk], a1 = As[tok0 + 1][kk];
      float4 bv = *(float4*)&Bs[kk][e0];
      double da0 = (double)a0, da1 = (double)a1;
      double b0 = (double)bv.x, b1 = (double)bv.y, b2 = (double)bv.z, b3 = (double)bv.w;
      acc[0][0] += da0 * b0; acc[0][1] += da0 * b1; acc[0][2] += da0 * b2; acc[0][3] += da0 * b3;
      acc[1][0] += da1 * b0; acc[1][1] += da1 * b1; acc[1][2] += da1 * b2; acc[1][3] += da1 * b3;
    }
    __syncthreads();
  }

  // dump fp64 logits to LDS (aliases As/Bs — all reads drained by last sync)
#pragma unroll
  for (int i = 0; i < 2; ++i)
#pragma unroll
    for (int j = 0; j < 4; ++j) Ld[tok0 + i][e0 + j] = acc[i][j];
  __syncthreads();

  // softmax/top2: 4 waves, 8 tokens each; lane = expert
  const int wave = t >> 6;
  const int lane = t & 63;
  const int b = tokBase >> 12;  // /4096 (blocks never span batches)
  float densacc = 0.f, zacc = 0.f;

  for (int s = 0; s < 8; ++s) {
    const int tok = wave * 8 + s;
    const double l = Ld[tok][lane];

    // argmax (first-index tie-break) in fp64
    double mv = l; int mi = lane;
#pragma unroll
    for (int off = 32; off; off >>= 1) {
      double ov = __shfl_xor(mv, off);
      int oi = __shfl_xor(mi, off);
      if (ov > mv || (ov == mv && oi < mi)) { mv = ov; mi = oi; }
    }
    float p = expf((float)(l - mv));
    float sum = p;
#pragma unroll
    for (int off = 32; off; off >>= 1) sum += __shfl_xor(sum, off);

    // second argmax excluding mi
    double l2 = (lane == mi) ? -1.0e300 : l;
    double mv2 = l2; int mi2 = lane;
#pragma unroll
    for (int off = 32; off; off >>= 1) {
      double ov = __shfl_xor(mv2, off);
      int oi = __shfl_xor(mi2, off);
      if (ov > mv2 || (ov == mv2 && oi < mi2)) { mv2 = ov; mi2 = oi; }
    }

    float gate1 = 1.0f / sum;                        // exp(0)/sum
    float gate2 = expf((float)(mv2 - mv)) / sum;
    float denom = gate1 + gate2 + 1e-9f;
    float g1n = gate1 / denom, g2n = gate2 / denom;
    int i2eff = (g2n > 0.2f) ? mi2 : -1;             // second-expert threshold policy
    float lse = (float)mv + logf(sum);

    densacc += p;                                    // density_proxy sum (expert = lane)
    if (lane == 0) {
      const int gt = tokBase + tok;
      idx1[gt] = mi; idx2[gt] = i2eff;
      g1o[gt] = g1n; g2o[gt] = g2n;
      zacc += lse;
    }
  }
  atomicAdd(&dens[(b << 6) + lane], densacc);
  if (lane == 0) atomicAdd(zsum, zacc);
}

// Kernel 2: scan + scatter + losses. One block (256 thr) per (b,e).
// Wave w scans tokens [w*1024,(w+1)*1024) caching ballots in registers;
// block-level prefix via LDS; matched entries written straight to d_out.
__global__ __launch_bounds__(256) void scan_scatter(
    const int* __restrict__ idx1, const int* __restrict__ idx2,
    const float* __restrict__ g1, const float* __restrict__ g2,
    const float* __restrict__ dens, const float* __restrict__ zsum,
    float* __restrict__ out, size_t half) {
  const int bid = blockIdx.x;          // 0..255 = b*64 + e
  const int b = bid >> 6, e = bid & 63;
  const int wv = threadIdx.x >> 6, lane = threadIdx.x & 63;
  const int tokBase = b * N_DIM + wv * 1024;
  const unsigned long long lmask = (1ull << lane) - 1ull;
  __shared__ int wcnt[4];

  float* dispatch = out;
  float* combine = out + half;
  unsigned long long bal[16];

  // ---- phase 1: top-1 ----
  int c = 0;
#pragma unroll
  for (int ch = 0; ch < 16; ++ch) {
    bool m = (idx1[tokBase + ch * 64 + lane] == e);
    bal[ch] = __ballot(m);
    c += __popcll(bal[ch]);
  }
  if (lane == 0) wcnt[wv] = c;
  __syncthreads();
  int pre = 0, tot = 0;
#pragma unroll
  for (int wvi = 0; wvi < 4; ++wvi) {
    int v = wcnt[wvi];
    if (wvi < wv) pre += v;
    tot += v;
  }
  int run = pre;
#pragma unroll
  for (int ch = 0; ch < 16; ++ch) {
    unsigned long long bb = bal[ch];
    if ((bb >> lane) & 1ull) {
      int p = run + __popcll(bb & lmask);
      if (p < CAP) {
        int tok = tokBase + ch * 64 + lane;
        size_t off = ((size_t)tok * E_DIM + e) * CAP + p;
        dispatch[off] = 1.0f;
        combine[off] = g1[tok];
      }
    }
    run += __popcll(bb);
  }
  __syncthreads();   // wcnt reuse

  // ---- phase 2: top-2, offset by min(tot, CAP) ----
  const int off0 = tot < CAP ? tot : CAP;
  int c2 = 0;
#pragma unroll
  for (int ch = 0; ch < 16; ++ch) {
    bool m = (idx2[tokBase + ch * 64 + lane] == e);
    bal[ch] = __ballot(m);
    c2 += __popcll(bal[ch]);
  }
  if (lane == 0) wcnt[wv] = c2;
  __syncthreads();
  int pre2 = 0;
#pragma unroll
  for (int wvi = 0; wvi < 4; ++wvi)
    if (wvi < wv) pre2 += wcnt[wvi];
  int run2 = off0 + pre2;
#pragma unroll
  for (int ch = 0; ch < 16; ++ch) {
    unsigned long long bb = bal[ch];
    if ((bb >> lane) & 1ull) {
      int p = run2 + __popcll(bb & lmask);
      if (p < CAP) {
        int tok = tokBase + ch * 64 + lane;
        size_t off = ((size_t)tok * E_DIM + e) * CAP + p;
        dispatch[off] = 1.0f;
        combine[off] = g2[tok];
      }
    }
    run2 += __popcll(bb);
  }

  // ---- losses ----
  if (threadIdx.x == 0) {
    // loss = sum_{b,e} dens[b,e] * cnt1_pre[b,e] / 1048576
    atomicAdd(&out[2 * half], dens[bid] * (float)tot * (1.0f / 1048576.0f));
    if (bid == 0) out[2 * half + 1] = zsum[0] * 0.25f;
  }
}

extern "C" void kernel_launch(void* const* d_in, const int* in_sizes, int n_in,
                              void* d_out, int out_size, void* d_ws, size_t ws_size,
                              hipStream_t stream) {
  const float* x = (const float*)d_in[0];
  const float* w = (const float*)d_in[1];
  float* out = (float*)d_out;
  char* ws = (char*)d_ws;

  int*   idx1 = (int*)(ws + WS_IDX1);
  int*   idx2 = (int*)(ws + WS_IDX2);
  float* g1   = (float*)(ws + WS_G1);
  float* g2   = (float*)(ws + WS_G2);
  float* dens = (float*)(ws + WS_DENS);
  float* zsum = (float*)(ws + WS_ZSUM);

  const size_t half = ((size_t)out_size - 2) / 2;  // 134217728

  // zero the tiny atomic accumulators (dens[256] + zsum)
  hipMemsetAsync(ws + WS_DENS, 0, 257 * sizeof(float), stream);

  // gating (blocks 0..511) overlapped with output zeroing (blocks 512..8703)
  fused_gating_zero<<<GATE_BLOCKS + ZERO_BLOCKS, 256, 0, stream>>>(
      x, w, idx1, idx2, g1, g2, dens, zsum, out, half);

  scan_scatter<<<B_DIM * E_DIM, 256, 0, stream>>>(idx1, idx2, g1, g2,
                                                  dens, zsum, out, half);
}